// Round 1
// 144.967 us; speedup vs baseline: 1.0698x; 1.0698x over previous
//
#include <hip/hip_runtime.h>

#define BATCH 4096
#define D_IN 1024
#define D_OUT 1024
#define N_EXPERTS 8

#define TM 64
#define TN 128
#define TK 32
#define MAX_TILES 71   // sum ceil(c_e/64) <= 64 + 7

// ws layout (int32 slots)
#define WS_PERM    0       // [4096]
#define WS_STARTS  4096    // [9]
#define WS_TILE_E  4112    // [71]
#define WS_TILE_M  4200    // [71]
#define WS_NTILES  4288    // [1]

typedef __attribute__((ext_vector_type(8))) short short8;   // 8 x bf16 (4 VGPRs)
typedef __attribute__((ext_vector_type(4))) float f32x4;

// ---------------------------------------------------------------------------
// Group samples by expert + build 64-row tile list. One block.
// ---------------------------------------------------------------------------
__global__ void group_kernel(const int* __restrict__ actions, int* __restrict__ ws) {
    __shared__ int cnt[N_EXPERTS];
    __shared__ int base[N_EXPERTS];
    const int t = threadIdx.x;
    if (t < N_EXPERTS) cnt[t] = 0;
    __syncthreads();
    for (int i = t; i < BATCH; i += 256) atomicAdd(&cnt[actions[i]], 1);
    __syncthreads();
    if (t == 0) {
        int s = 0, nt = 0;
        for (int e = 0; e < N_EXPERTS; ++e) {
            const int c = cnt[e];
            base[e] = s;
            ws[WS_STARTS + e] = s;
            for (int m0 = 0; m0 < c; m0 += TM) {
                ws[WS_TILE_E + nt] = e;
                ws[WS_TILE_M + nt] = m0;
                ++nt;
            }
            s += c;
            cnt[e] = 0;
        }
        ws[WS_STARTS + N_EXPERTS] = s;
        ws[WS_NTILES] = nt;
    }
    __syncthreads();
    for (int i = t; i < BATCH; i += 256) {
        const int a = actions[i];
        const int pos = base[a] + atomicAdd(&cnt[a], 1);
        ws[WS_PERM + pos] = i;
    }
}

// fp32 -> bf16 hi/lo split (truncation; lo captures next 8 mantissa bits)
__device__ __forceinline__ void cvt8(const float4 a, const float4 b,
                                     short8& h, short8& l) {
    float f[8] = {a.x, a.y, a.z, a.w, b.x, b.y, b.z, b.w};
#pragma unroll
    for (int i = 0; i < 8; ++i) {
        const unsigned u = __float_as_uint(f[i]);
        h[i] = (short)(u >> 16);
        const float r = f[i] - __uint_as_float(u & 0xffff0000u);
        l[i] = (short)(__float_as_uint(r) >> 16);
    }
}

// ---------------------------------------------------------------------------
// Split-bf16 MFMA GEMM over gathered rows.
// TM=64 x TN=128 tile / block; 4 waves in 2x2 grid, each a 32x64 quadrant
// as 2x4 grid of 16x16x32 MFMA tiles, 3 MFMA each (hi*hi + hi*lo + lo*hi).
//
// R-this-round changes (latency-bound fix; all pipes were <20%):
//  1. Register prefetch pipeline: K-tile k+1's 6 global_load_dwordx4 are
//     issued right after barrier-1 and consumed at the TOP of the next
//     iteration, hiding HBM/L2 latency under ds_read+MFMA. End-of-iter
//     barrier is a raw s_barrier (no vmcnt(0) drain -> prefetch stays in
//     flight across it); barrier-1 keeps __syncthreads (vmcnt already 0
//     there, so its drain is free).
//  2. LDS slot XOR-swizzle slot^=( (slot>>4)<<1 ): kills the 4-way bank
//     conflict on ds_write_b128 (bank was f(row&7) only, independent of
//     the k-octet). Loop-invariant addressing; reads stay 2-way (free).
// ---------------------------------------------------------------------------
__global__ __launch_bounds__(256) void moe_gemm(
    const float* __restrict__ xs, const float* __restrict__ W,
    const float* __restrict__ bias, const int* __restrict__ ws,
    float* __restrict__ out)
{
    const int tix = blockIdx.y;
    if (tix >= ws[WS_NTILES]) return;
    const int e   = ws[WS_TILE_E + tix];
    const int m0  = ws[WS_TILE_M + tix];
    const int s0  = ws[WS_STARTS + e];
    const int cnt = ws[WS_STARTS + e + 1] - s0;
    const int n0  = blockIdx.x * TN;

    __shared__ short Ahi[TM * TK];   // fragment-major: [tile(4)][slot(64)][8]
    __shared__ short Alo[TM * TK];
    __shared__ short Bhi[TN * TK];   // [tile(8)][slot(64)][8]
    __shared__ short Blo[TN * TK];
    __shared__ int   rows_s[TM];

    const int t = threadIdx.x;
    if (t < TM) {
        const int r = m0 + t;
        rows_s[t] = (r < cnt) ? ws[WS_PERM + s0 + r] : -1;
    }
    __syncthreads();

    const int lane = t & 63;
    const int wave = t >> 6;
    const int wm = (wave & 1) * 32;   // quadrant m base (0 or 32)
    const int wn = (wave >> 1) * 64;  // quadrant n base (0 or 64)

    const float zf = 0.f;
    f32x4 acc[2][4];
#pragma unroll
    for (int mi = 0; mi < 2; ++mi)
#pragma unroll
        for (int nj = 0; nj < 4; ++nj)
            acc[mi][nj] = (f32x4){zf, zf, zf, zf};

    const float* Wb = W + (size_t)e * (D_OUT * (size_t)D_IN) + (size_t)n0 * D_IN;

    const int j  = t & 3;    // k-octet: k = j*8 .. j*8+7
    const int rr = t >> 2;   // 0..63

    // A-row pointer (row may be -1)
    const int arow = rows_s[rr];
    const float* aptr = (arow >= 0) ? (xs + (size_t)arow * D_IN + j * 8) : nullptr;

    // Swizzled store offsets (loop-invariant). slot = j*16 + row; slot ^= j<<1.
    const int slotA   = (j * 16 + (rr & 15)) ^ (j << 1);
    const int aoff_st = (rr >> 4) * 512 + slotA * 8;   // shorts
    const int boff0   = aoff_st;                        // n = rr      (same formula)
    const int boff1   = aoff_st + 4 * 512;              // n = 64 + rr (tile +4)

    // W row pointers (loop-invariant)
    const float* qb0 = Wb + (size_t)rr * D_IN + j * 8;
    const float* qb1 = Wb + (size_t)(64 + rr) * D_IN + j * 8;

    // Swizzled read offset: lane l needs slot l -> stored at l ^ ((l>>4)<<1)
    const int rds = (lane ^ ((lane >> 4) << 1)) * 8;    // shorts

    // --- prologue: load K-tile 0 into registers ---
    float4 ra0 = make_float4(0.f, 0.f, 0.f, 0.f), ra1 = ra0;
    if (aptr) { ra0 = *(const float4*)(aptr);     ra1 = *(const float4*)(aptr + 4); }
    float4 rb0 = *(const float4*)(qb0),           rb1 = *(const float4*)(qb0 + 4);
    float4 rb2 = *(const float4*)(qb1),           rb3 = *(const float4*)(qb1 + 4);

    for (int k0 = 0; ; ) {
        // --- stage current tile from registers to LDS ---
        {
            short8 h, l;
            cvt8(ra0, ra1, h, l);
            *(short8*)&Ahi[aoff_st] = h;
            *(short8*)&Alo[aoff_st] = l;
            cvt8(rb0, rb1, h, l);
            *(short8*)&Bhi[boff0] = h;
            *(short8*)&Blo[boff0] = l;
            cvt8(rb2, rb3, h, l);
            *(short8*)&Bhi[boff1] = h;
            *(short8*)&Blo[boff1] = l;
        }
        __syncthreads();   // LDS visible; vmcnt already 0 here (drain is free)

        // --- issue next tile's global loads (latency hides under MFMA) ---
        const int kn = k0 + TK;
        if (kn < D_IN) {
            if (aptr) {
                ra0 = *(const float4*)(aptr + kn);
                ra1 = *(const float4*)(aptr + kn + 4);
            }
            rb0 = *(const float4*)(qb0 + kn); rb1 = *(const float4*)(qb0 + kn + 4);
            rb2 = *(const float4*)(qb1 + kn); rb3 = *(const float4*)(qb1 + kn + 4);
        }

        // --- fragments + MFMA ---
        short8 ah[2], al[2], bh[4], bl[4];
#pragma unroll
        for (int i2 = 0; i2 < 2; ++i2) {
            const int aoff = ((wm >> 4) + i2) * 512 + rds;
            ah[i2] = *(const short8*)&Ahi[aoff];
            al[i2] = *(const short8*)&Alo[aoff];
        }
#pragma unroll
        for (int i2 = 0; i2 < 4; ++i2) {
            const int boff = ((wn >> 4) + i2) * 512 + rds;
            bh[i2] = *(const short8*)&Bhi[boff];
            bl[i2] = *(const short8*)&Blo[boff];
        }
#pragma unroll
        for (int mi = 0; mi < 2; ++mi)
#pragma unroll
            for (int nj = 0; nj < 4; ++nj) {
                acc[mi][nj] = __builtin_amdgcn_mfma_f32_16x16x32_bf16(ah[mi], bh[nj], acc[mi][nj], 0, 0, 0);
                acc[mi][nj] = __builtin_amdgcn_mfma_f32_16x16x32_bf16(ah[mi], bl[nj], acc[mi][nj], 0, 0, 0);
                acc[mi][nj] = __builtin_amdgcn_mfma_f32_16x16x32_bf16(al[mi], bh[nj], acc[mi][nj], 0, 0, 0);
            }

        if (kn >= D_IN) break;
        k0 = kn;
        // Raw barrier: no vmcnt(0) drain -> prefetch loads stay in flight.
        // "memory" clobber pins next-iter ds_writes below / loads above it.
        // All ds_reads above are already consumed by the MFMAs (lgkmcnt
        // waits inserted at use), so no explicit waitcnt is needed here.
        asm volatile("s_barrier" ::: "memory");
    }

    // Epilogue: C/D layout col=lane&15, row=(lane>>4)*4+reg
    const int cl = lane & 15;
    const int qd = lane >> 4;
    float bv[4];
#pragma unroll
    for (int nj = 0; nj < 4; ++nj)
        bv[nj] = bias[e * D_OUT + n0 + wn + nj * 16 + cl];
#pragma unroll
    for (int mi = 0; mi < 2; ++mi) {
#pragma unroll
        for (int reg = 0; reg < 4; ++reg) {
            const int mloc = wm + mi * 16 + qd * 4 + reg;
            const int r = rows_s[mloc];
            if (r >= 0) {
                float* orow = out + (size_t)r * D_OUT + n0 + wn + cl;
#pragma unroll
                for (int nj = 0; nj < 4; ++nj)
                    orow[nj * 16] = acc[mi][nj][reg] + bv[nj];
            }
        }
    }
}

// ---------------------------------------------------------------------------
// Passthrough tail outputs (unchanged — validated).
// ---------------------------------------------------------------------------
__global__ void meta_float_kernel(const int* __restrict__ mxs,
                                  const int* __restrict__ actions,
                                  float* __restrict__ out) {
    const int i = blockIdx.x * 256 + threadIdx.x;
    if (i < BATCH) {
        out[BATCH * D_OUT + i] = (float)mxs[i];
        out[BATCH * D_OUT + BATCH + i] = (float)actions[i];
    }
}

__global__ void meta_raw64_kernel(const int* __restrict__ mxs,
                                  const int* __restrict__ actions,
                                  float* __restrict__ out) {
    const int i = blockIdx.x * 256 + threadIdx.x;
    if (i < BATCH) {
        out[BATCH * D_OUT + i] = (float)mxs[i];
        long long* a64 = (long long*)(out + BATCH * D_OUT + BATCH);
        a64[i] = (long long)actions[i];
    }
}

extern "C" void kernel_launch(void* const* d_in, const int* in_sizes, int n_in,
                              void* d_out, int out_size, void* d_ws, size_t ws_size,
                              hipStream_t stream) {
    const float* xs      = (const float*)d_in[0];
    const int*   mxs     = (const int*)d_in[1];
    const int*   actions = (const int*)d_in[2];
    const float* W       = (const float*)d_in[3];
    const float* bias    = (const float*)d_in[4];
    float* out = (float*)d_out;
    int*   ws  = (int*)d_ws;

    group_kernel<<<1, 256, 0, stream>>>(actions, ws);

    dim3 grid(D_OUT / TN, MAX_TILES, 1);
    moe_gemm<<<grid, 256, 0, stream>>>(xs, W, bias, ws, out);

    const int metaOff = BATCH * D_OUT;
    if (out_size >= metaOff + 3 * BATCH) {
        meta_raw64_kernel<<<(BATCH + 255) / 256, 256, 0, stream>>>(mxs, actions, out);
    } else if (out_size >= metaOff + 2 * BATCH) {
        meta_float_kernel<<<(BATCH + 255) / 256, 256, 0, stream>>>(mxs, actions, out);
    }
}

// Round 2
// 141.682 us; speedup vs baseline: 1.0946x; 1.0232x over previous
//
#include <hip/hip_runtime.h>

#define BATCH 4096
#define D_IN 1024
#define D_OUT 1024
#define N_EXPERTS 8

#define TM 64
#define TN 128
#define TK 32
#define MAX_TILES 71   // sum ceil(c_e/64) <= 64 + 7

// ws layout (int32 slots)
#define WS_PERM    0       // [4096]
#define WS_STARTS  4096    // [9]
#define WS_TILE_E  4112    // [71]
#define WS_TILE_M  4200    // [71]
#define WS_NTILES  4288    // [1]

typedef __attribute__((ext_vector_type(8))) short short8;   // 8 x bf16 (4 VGPRs)
typedef __attribute__((ext_vector_type(4))) float f32x4;

// ---------------------------------------------------------------------------
// Group samples by expert + build 64-row tile list. One block.
// ---------------------------------------------------------------------------
__global__ void group_kernel(const int* __restrict__ actions, int* __restrict__ ws) {
    __shared__ int cnt[N_EXPERTS];
    __shared__ int base[N_EXPERTS];
    const int t = threadIdx.x;
    if (t < N_EXPERTS) cnt[t] = 0;
    __syncthreads();
    for (int i = t; i < BATCH; i += 256) atomicAdd(&cnt[actions[i]], 1);
    __syncthreads();
    if (t == 0) {
        int s = 0, nt = 0;
        for (int e = 0; e < N_EXPERTS; ++e) {
            const int c = cnt[e];
            base[e] = s;
            ws[WS_STARTS + e] = s;
            for (int m0 = 0; m0 < c; m0 += TM) {
                ws[WS_TILE_E + nt] = e;
                ws[WS_TILE_M + nt] = m0;
                ++nt;
            }
            s += c;
            cnt[e] = 0;
        }
        ws[WS_STARTS + N_EXPERTS] = s;
        ws[WS_NTILES] = nt;
    }
    __syncthreads();
    for (int i = t; i < BATCH; i += 256) {
        const int a = actions[i];
        const int pos = base[a] + atomicAdd(&cnt[a], 1);
        ws[WS_PERM + pos] = i;
    }
}

// fp32 -> bf16 hi/lo split (truncation; lo captures next 8 mantissa bits)
__device__ __forceinline__ void cvt8(const float4 a, const float4 b,
                                     short8& h, short8& l) {
    float f[8] = {a.x, a.y, a.z, a.w, b.x, b.y, b.z, b.w};
#pragma unroll
    for (int i = 0; i < 8; ++i) {
        const unsigned u = __float_as_uint(f[i]);
        h[i] = (short)(u >> 16);
        const float r = f[i] - __uint_as_float(u & 0xffff0000u);
        l[i] = (short)(__float_as_uint(r) >> 16);
    }
}

// ---------------------------------------------------------------------------
// Split-bf16 MFMA GEMM over gathered rows.
// TM=64 x TN=128 tile / block; 4 waves in 2x2 grid, each a 32x64 quadrant
// as 2x4 grid of 16x16x32 MFMA tiles, 3 MFMA each (hi*hi + hi*lo + lo*hi).
//
// R2: DOUBLE-BUFFERED LDS software pipeline. R1 removed bank conflicts and
// added register prefetch, but cvt+ds_write -> barrier -> ds_read -> MFMA
// stayed one serial chain per wave (all pipes <35%, occupancy grid-limited
// at 2 blocks/CU). Now: two LDS buffers, unroll-by-2 with two NAMED register
// sets (rule #20). Per iter: issue next loads -> ds_read+MFMA buf[cur] ->
// cvt+ds_write prev regs into buf[cur^1] -> lgkmcnt(0);s_barrier (raw: the
// prefetch loads stay in flight across the barrier, T4). MFMA(tile k) and
// cvt(tile k+1) are now independent -> VALU/MFMA overlap.
// ---------------------------------------------------------------------------
__global__ __launch_bounds__(256) void moe_gemm(
    const float* __restrict__ xs, const float* __restrict__ W,
    const float* __restrict__ bias, const int* __restrict__ ws,
    float* __restrict__ out)
{
    const int tix = blockIdx.y;
    if (tix >= ws[WS_NTILES]) return;
    const int e   = ws[WS_TILE_E + tix];
    const int m0  = ws[WS_TILE_M + tix];
    const int s0  = ws[WS_STARTS + e];
    const int cnt = ws[WS_STARTS + e + 1] - s0;
    const int n0  = blockIdx.x * TN;

    // fragment-major: [tile][slot(64)][8], slot XOR-swizzled (R1, conflicts=0)
    __shared__ short Ahi[2][TM * TK];
    __shared__ short Alo[2][TM * TK];
    __shared__ short Bhi[2][TN * TK];
    __shared__ short Blo[2][TN * TK];
    __shared__ int   rows_s[TM];

    const int t = threadIdx.x;
    if (t < TM) {
        const int r = m0 + t;
        rows_s[t] = (r < cnt) ? ws[WS_PERM + s0 + r] : -1;
    }
    __syncthreads();

    const int lane = t & 63;
    const int wave = t >> 6;
    const int wm = (wave & 1) * 32;   // quadrant m base (0 or 32)
    const int wn = (wave >> 1) * 64;  // quadrant n base (0 or 64)

    const float zf = 0.f;
    f32x4 acc[2][4];
#pragma unroll
    for (int mi = 0; mi < 2; ++mi)
#pragma unroll
        for (int nj = 0; nj < 4; ++nj)
            acc[mi][nj] = (f32x4){zf, zf, zf, zf};

    const float* Wb = W + (size_t)e * (D_OUT * (size_t)D_IN) + (size_t)n0 * D_IN;

    const int j  = t & 3;    // k-octet: k = j*8 .. j*8+7
    const int rr = t >> 2;   // 0..63

    const int arow = rows_s[rr];
    const float* aptr = (arow >= 0) ? (xs + (size_t)arow * D_IN + j * 8) : nullptr;

    // Swizzled store offsets (loop-invariant). slot = j*16 + row; slot ^= j<<1.
    const int slotA   = (j * 16 + (rr & 15)) ^ (j << 1);
    const int aoff_st = (rr >> 4) * 512 + slotA * 8;   // shorts
    const int boff0   = aoff_st;                        // n = rr
    const int boff1   = aoff_st + 4 * 512;              // n = 64 + rr

    const float* qb0 = Wb + (size_t)rr * D_IN + j * 8;
    const float* qb1 = Wb + (size_t)(64 + rr) * D_IN + j * 8;

    // Swizzled read offset: lane l's slot stored at l ^ ((l>>4)<<1)
    const int rds = (lane ^ ((lane >> 4) << 1)) * 8;    // shorts

#define LOAD_SET(A0, A1, B0, B1, B2, B3, KOFF) do {                          \
        const int _k = (KOFF);                                               \
        if (aptr) {                                                          \
            A0 = *(const float4*)(aptr + _k);                                \
            A1 = *(const float4*)(aptr + _k + 4);                            \
        }                                                                    \
        B0 = *(const float4*)(qb0 + _k); B1 = *(const float4*)(qb0 + _k + 4);\
        B2 = *(const float4*)(qb1 + _k); B3 = *(const float4*)(qb1 + _k + 4);\
    } while (0)

#define CVT_STORE_SET(A0, A1, B0, B1, B2, B3, BUF) do {                      \
        short8 _h, _l;                                                       \
        cvt8(A0, A1, _h, _l);                                                \
        *(short8*)&Ahi[BUF][aoff_st] = _h; *(short8*)&Alo[BUF][aoff_st] = _l;\
        cvt8(B0, B1, _h, _l);                                                \
        *(short8*)&Bhi[BUF][boff0] = _h;   *(short8*)&Blo[BUF][boff0] = _l;  \
        cvt8(B2, B3, _h, _l);                                                \
        *(short8*)&Bhi[BUF][boff1] = _h;   *(short8*)&Blo[BUF][boff1] = _l;  \
    } while (0)

#define FRAG_MFMA(BUF) do {                                                  \
        short8 ah[2], al[2], bh[4], bl[4];                                   \
        _Pragma("unroll")                                                    \
        for (int i2 = 0; i2 < 2; ++i2) {                                     \
            const int aoff = ((wm >> 4) + i2) * 512 + rds;                   \
            ah[i2] = *(const short8*)&Ahi[BUF][aoff];                        \
            al[i2] = *(const short8*)&Alo[BUF][aoff];                        \
        }                                                                    \
        _Pragma("unroll")                                                    \
        for (int i2 = 0; i2 < 4; ++i2) {                                     \
            const int boff = ((wn >> 4) + i2) * 512 + rds;                   \
            bh[i2] = *(const short8*)&Bhi[BUF][boff];                        \
            bl[i2] = *(const short8*)&Blo[BUF][boff];                        \
        }                                                                    \
        _Pragma("unroll")                                                    \
        for (int mi = 0; mi < 2; ++mi)                                       \
            _Pragma("unroll")                                                \
            for (int nj = 0; nj < 4; ++nj) {                                 \
                acc[mi][nj] = __builtin_amdgcn_mfma_f32_16x16x32_bf16(ah[mi], bh[nj], acc[mi][nj], 0, 0, 0); \
                acc[mi][nj] = __builtin_amdgcn_mfma_f32_16x16x32_bf16(ah[mi], bl[nj], acc[mi][nj], 0, 0, 0); \
                acc[mi][nj] = __builtin_amdgcn_mfma_f32_16x16x32_bf16(al[mi], bh[nj], acc[mi][nj], 0, 0, 0); \
            }                                                                \
    } while (0)

    // Raw barrier: drains LDS ops (required for buffer handoff) but leaves
    // the prefetch global loads in flight (no vmcnt drain).
#define PIPE_BARRIER() asm volatile("s_waitcnt lgkmcnt(0)\n\ts_barrier" ::: "memory")

    // Two named prefetch register sets (X, Y) — no runtime indexing.
    float4 ax0 = make_float4(0.f, 0.f, 0.f, 0.f), ax1 = ax0;
    float4 bx0, bx1, bx2, bx3;
    float4 ay0 = make_float4(0.f, 0.f, 0.f, 0.f), ay1 = ay0;
    float4 by0, by1, by2, by3;

    // --- prologue: tile0 -> buf0; tile1 -> regsX ---
    LOAD_SET(ax0, ax1, bx0, bx1, bx2, bx3, 0);
    CVT_STORE_SET(ax0, ax1, bx0, bx1, bx2, bx3, 0);
    LOAD_SET(ax0, ax1, bx0, bx1, bx2, bx3, TK);
    PIPE_BARRIER();   // buf0 ready; t1 loads stay in flight

    // --- main loop: 15 pairs; pair i computes tiles 2i (buf0) and 2i+1 (buf1)
    //     even: compute buf0, load tile 2i+2 -> Y, stage X (tile 2i+1) -> buf1
    //     odd : compute buf1, load tile 2i+3 -> X, stage Y (tile 2i+2) -> buf0
    int ke = 2 * TK;
#pragma unroll 1
    for (int i = 0; i < 15; ++i) {
        {   // even
            LOAD_SET(ay0, ay1, by0, by1, by2, by3, ke);
            FRAG_MFMA(0);
            CVT_STORE_SET(ax0, ax1, bx0, bx1, bx2, bx3, 1);
            PIPE_BARRIER();
        }
        {   // odd
            LOAD_SET(ax0, ax1, bx0, bx1, bx2, bx3, ke + TK);
            FRAG_MFMA(1);
            CVT_STORE_SET(ay0, ay1, by0, by1, by2, by3, 0);
            PIPE_BARRIER();
        }
        ke += 2 * TK;
    }
    // --- epilogue: tile30 in buf0, tile31 in regsX ---
    {
        FRAG_MFMA(0);
        CVT_STORE_SET(ax0, ax1, bx0, bx1, bx2, bx3, 1);
        PIPE_BARRIER();
    }
    {
        FRAG_MFMA(1);
    }

#undef LOAD_SET
#undef CVT_STORE_SET
#undef FRAG_MFMA
#undef PIPE_BARRIER

    // Epilogue: C/D layout col=lane&15, row=(lane>>4)*4+reg
    const int cl = lane & 15;
    const int qd = lane >> 4;
    float bv[4];
#pragma unroll
    for (int nj = 0; nj < 4; ++nj)
        bv[nj] = bias[e * D_OUT + n0 + wn + nj * 16 + cl];
#pragma unroll
    for (int mi = 0; mi < 2; ++mi) {
#pragma unroll
        for (int reg = 0; reg < 4; ++reg) {
            const int mloc = wm + mi * 16 + qd * 4 + reg;
            const int r = rows_s[mloc];
            if (r >= 0) {
                float* orow = out + (size_t)r * D_OUT + n0 + wn + cl;
#pragma unroll
                for (int nj = 0; nj < 4; ++nj)
                    orow[nj * 16] = acc[mi][nj][reg] + bv[nj];
            }
        }
    }
}

// ---------------------------------------------------------------------------
// Passthrough tail outputs (unchanged — validated).
// ---------------------------------------------------------------------------
__global__ void meta_float_kernel(const int* __restrict__ mxs,
                                  const int* __restrict__ actions,
                                  float* __restrict__ out) {
    const int i = blockIdx.x * 256 + threadIdx.x;
    if (i < BATCH) {
        out[BATCH * D_OUT + i] = (float)mxs[i];
        out[BATCH * D_OUT + BATCH + i] = (float)actions[i];
    }
}

__global__ void meta_raw64_kernel(const int* __restrict__ mxs,
                                  const int* __restrict__ actions,
                                  float* __restrict__ out) {
    const int i = blockIdx.x * 256 + threadIdx.x;
    if (i < BATCH) {
        out[BATCH * D_OUT + i] = (float)mxs[i];
        long long* a64 = (long long*)(out + BATCH * D_OUT + BATCH);
        a64[i] = (long long)actions[i];
    }
}

extern "C" void kernel_launch(void* const* d_in, const int* in_sizes, int n_in,
                              void* d_out, int out_size, void* d_ws, size_t ws_size,
                              hipStream_t stream) {
    const float* xs      = (const float*)d_in[0];
    const int*   mxs     = (const int*)d_in[1];
    const int*   actions = (const int*)d_in[2];
    const float* W       = (const float*)d_in[3];
    const float* bias    = (const float*)d_in[4];
    float* out = (float*)d_out;
    int*   ws  = (int*)d_ws;

    group_kernel<<<1, 256, 0, stream>>>(actions, ws);

    dim3 grid(D_OUT / TN, MAX_TILES, 1);
    moe_gemm<<<grid, 256, 0, stream>>>(xs, W, bias, ws, out);

    const int metaOff = BATCH * D_OUT;
    if (out_size >= metaOff + 3 * BATCH) {
        meta_raw64_kernel<<<(BATCH + 255) / 256, 256, 0, stream>>>(mxs, actions, out);
    } else if (out_size >= metaOff + 2 * BATCH) {
        meta_float_kernel<<<(BATCH + 255) / 256, 256, 0, stream>>>(mxs, actions, out);
    }
}